// Round 3
// baseline (92.123 us; speedup 1.0000x reference)
//
#include <hip/hip_runtime.h>
#include <float.h>

// Problem constants (from reference setup_inputs):
//   input: (1, C=64, 48, 48, 48) fp32
//   rois:  (1, N=16, 7) int32  [batch, sx, sy, sz, ex, ey, ez]
//   out:   (N, C, 4, 4, 4) fp32 = 65536 elements
// ROI edge lengths are in [8, 24] (rng.integers(8, 25)).
#define NC 64
#define DIM 48
#define NROI 16
#define MAXL 24
// LDS box: [lx][ly][lz+1] packed with runtime strides; worst case 24*24*25
#define LDS_FLOATS (MAXL * MAXL * (MAXL + 1))   // 14400 floats = 57.6 KB

__global__ __launch_bounds__(256) void roipool3d_kernel(
    const float* __restrict__ feat,   // (C, 48, 48, 48)
    const int*   __restrict__ rois,   // (N, 7)
    float*       __restrict__ out)    // (N, C, 4, 4, 4)
{
    __shared__ float box[LDS_FLOATS];

    int t = threadIdx.x;
    int c = blockIdx.x & (NC - 1);
    int n = blockIdx.x >> 6;

    // ROI params: block-uniform -> scalar
    const int* r = rois + n * 7;
    int sx = r[1], sy = r[2], sz = r[3];
    int lx = r[4] + 1 - sx;
    int ly = r[5] + 1 - sy;
    int lz = r[6] + 1 - sz;
    int lzp = lz + 1;                 // padded LDS z-stride (bank spread)

    const float* base = feat + (size_t)c * (DIM * DIM * DIM)
                      + sx * (DIM * DIM) + sy * DIM + sz;

    // ---- Stage ROI box into LDS, coalesced: 32 lanes along z per row ----
    // 8 row-workers (t>>5), each walks rows rr = x*ly + y strided by 8.
    // ly >= 8 guarantees the initial row rw < ly -> x=0, y=rw (no division),
    // and each += 8 step wraps y at most once.
    {
        int zt = t & 31;
        int rw = t >> 5;
        int nrows = lx * ly;
        if (zt < lz) {
            int x = 0, y = rw;
            for (int rr = rw; rr < nrows; rr += 8) {
                box[rr * lzp + zt] = base[x * (DIM * DIM) + y * DIM + zt];
                y += 8;
                if (y >= ly) { y -= ly; ++x; }
            }
        }
    }
    __syncthreads();

    // ---- Compute: one quad (4 lanes) per output bin, reading LDS ----
    int bin = t >> 2;          // 0..63
    int p   = t & 3;
    int k = bin & 3;
    int j = (bin >> 2) & 3;
    int i = bin >> 4;

    // Local (box-relative) adaptive-pool bin bounds:
    // [floor(i*L/4), ceil((i+1)*L/4))
    int bx0 = (i * lx) >> 2,  bx1 = ((i + 1) * lx + 3) >> 2;
    int by0 = (j * ly) >> 2,  by1 = ((j + 1) * ly + 3) >> 2;
    int bz0 = (k * lz) >> 2,  bz1 = ((k + 1) * lz + 3) >> 2;

    // z-span per bin is 2..7, so lane p covers z = bz0+p and bz0+p+4 at most.
    float m0 = -FLT_MAX, m1 = -FLT_MAX;
    int z0 = bz0 + p;
    int z1 = z0 + 4;
    for (int x = bx0; x < bx1; ++x) {
        int rowx = x * ly;
        for (int y = by0; y < by1; ++y) {
            int rowa = (rowx + y) * lzp;
            if (z0 < bz1) m0 = fmaxf(m0, box[rowa + z0]);
            if (z1 < bz1) m1 = fmaxf(m1, box[rowa + z1]);
        }
    }
    float m = fmaxf(m0, m1);

    // quad reduce (lanes of a bin are consecutive)
    m = fmaxf(m, __shfl_xor(m, 1));
    m = fmaxf(m, __shfl_xor(m, 2));

    if (p == 0) out[(blockIdx.x << 6) + bin] = m;
}

extern "C" void kernel_launch(void* const* d_in, const int* in_sizes, int n_in,
                              void* d_out, int out_size, void* d_ws, size_t ws_size,
                              hipStream_t stream) {
    const float* feat = (const float*)d_in[0];
    const int*   rois = (const int*)d_in[1];
    float*       out  = (float*)d_out;

    roipool3d_kernel<<<dim3(NROI * NC), dim3(256), 0, stream>>>(feat, rois, out);
}

// Round 4
// 81.871 us; speedup vs baseline: 1.1252x; 1.1252x over previous
//
#include <hip/hip_runtime.h>
#include <float.h>

// Problem constants (from reference setup_inputs):
//   input: (1, C=64, 48, 48, 48) fp32
//   rois:  (1, N=16, 7) int32  [batch, sx, sy, sz, ex, ey, ez]
//   out:   (N, C, 4, 4, 4) fp32 = 65536 elements
// ROI edge lengths are in [8, 24], so per-bin z-span is in [2, 7].
#define NC 64
#define DIM 48
#define NROI 16

// One block per (n, c), 256 threads, no LDS (keeps 4+ blocks/CU resident).
// Quad (4 lanes) per output bin; lane p takes z = bz0+p and bz0+p+4 while
// the quad iterates the bin's (x,y) rows TOGETHER. Within a wave, lanes
// 0..15 = (j=0, k=0..3, p=0..3) read 16 consecutive floats tiling one
// y-row's z-run -> ~4 distinct rows per 64-lane load instead of ~64
// (round 2's layout). Same voxel count, ~8x fewer L1 cache-line walks.
__global__ __launch_bounds__(256) void roipool3d_kernel(
    const float* __restrict__ feat,   // (C, 48, 48, 48)
    const int*   __restrict__ rois,   // (N, 7)
    float*       __restrict__ out)    // (N, C, 4, 4, 4)
{
    int t = threadIdx.x;
    int bin = t >> 2;          // 0..63 -> (i,j,k)
    int p   = t & 3;           // z-offset lane within the quad
    int c = blockIdx.x & (NC - 1);
    int n = blockIdx.x >> 6;

    int k = bin & 3;
    int j = (bin >> 2) & 3;
    int i = bin >> 4;

    // ROI params: block-uniform -> scalar loads
    const int* r = rois + n * 7;
    int sx = r[1], sy = r[2], sz = r[3];
    int lx = r[4] + 1 - sx;
    int ly = r[5] + 1 - sy;
    int lz = r[6] + 1 - sz;

    // PyTorch adaptive-pool bin: [s + floor(i*L/4), s + ceil((i+1)*L/4))
    int bx0 = sx + ((i * lx) >> 2);
    int bx1 = sx + (((i + 1) * lx + 3) >> 2);
    int by0 = sy + ((j * ly) >> 2);
    int by1 = sy + (((j + 1) * ly + 3) >> 2);
    int bz0 = sz + ((k * lz) >> 2);
    int bz1 = sz + (((k + 1) * lz + 3) >> 2);

    const float* base = feat + (size_t)c * (DIM * DIM * DIM);

    // Lane p covers z0 = bz0+p and z1 = z0+4 (z-span <= 7). Predicated.
    int z0 = bz0 + p;
    int z1 = z0 + 4;
    bool e0 = (z0 < bz1);
    bool e1 = (z1 < bz1);

    float m0 = -FLT_MAX, m1 = -FLT_MAX;
    for (int x = bx0; x < bx1; ++x) {
        const float* px = base + x * (DIM * DIM);
        for (int y = by0; y < by1; ++y) {
            const float* row = px + y * DIM;
            if (e0) m0 = fmaxf(m0, row[z0]);
            if (e1) m1 = fmaxf(m1, row[z1]);
        }
    }
    float m = fmaxf(m0, m1);

    // quad reduce (lanes of a bin are consecutive)
    m = fmaxf(m, __shfl_xor(m, 1));
    m = fmaxf(m, __shfl_xor(m, 2));

    if (p == 0) out[(blockIdx.x << 6) + bin] = m;
}

extern "C" void kernel_launch(void* const* d_in, const int* in_sizes, int n_in,
                              void* d_out, int out_size, void* d_ws, size_t ws_size,
                              hipStream_t stream) {
    const float* feat = (const float*)d_in[0];
    const int*   rois = (const int*)d_in[1];
    float*       out  = (float*)d_out;

    roipool3d_kernel<<<dim3(NROI * NC), dim3(256), 0, stream>>>(feat, rois, out);
}

// Round 5
// 75.500 us; speedup vs baseline: 1.2202x; 1.0844x over previous
//
#include <hip/hip_runtime.h>
#include <float.h>

// Problem constants (from reference setup_inputs):
//   input: (1, C=64, 48, 48, 48) fp32
//   rois:  (1, N=16, 7) int32  [batch, sx, sy, sz, ex, ey, ez]
//   out:   (N, C, 4, 4, 4) fp32 = 65536 elements
// ROI edge lengths L in [8, 24] => per-axis bin span in [2, 7], lz in [8, 24].
#define NC 64
#define DIM 48
#define NROI 16
#define D2 (DIM * DIM)

// One WAVE per (n, c, i, j): 16384 waves (4096 blocks x 256 thr).
// Lane layout: rp = lane>>5 (row parity), zt = lane&31 (z offset, lz<=24<32).
// A single 64-lane load covers 2 whole rows' z-runs (coalesced, ~4 lines).
// 4 independent loads batched per iteration; avg box needs 2 iterations.
// Reduction: xor-32 shuffle (rows) + bpermute segmented max (z bins) —
// almost no serial dependent-load chain left.
__global__ __launch_bounds__(256) void roipool3d_kernel(
    const float* __restrict__ feat,   // (C, 48, 48, 48)
    const int*   __restrict__ rois,   // (N, 7)
    float*       __restrict__ out)    // (N, C, 4, 4, 4)
{
    int t = threadIdx.x;
    int lane = t & 63;
    int w = (blockIdx.x << 2) | (t >> 6);   // global wave id = (((n,c),i),j)
    int j = w & 3;
    int i = (w >> 2) & 3;
    int c = (w >> 4) & (NC - 1);
    int n = w >> 10;

    // ROI params: wave-uniform -> scalar
    const int* r = rois + n * 7;
    int sx = r[1], sy = r[2], sz = r[3];
    int lx = r[4] + 1 - sx;
    int ly = r[5] + 1 - sy;
    int lz = r[6] + 1 - sz;

    // x/y bin bounds (box-local): [floor(i*L/4), ceil((i+1)*L/4))
    int bx0 = (i * lx) >> 2, bx1 = ((i + 1) * lx + 3) >> 2;
    int by0 = (j * ly) >> 2, by1 = ((j + 1) * ly + 3) >> 2;
    int nx = bx1 - bx0, ny = by1 - by0;   // each in [2,7]
    int nrows = nx * ny;

    int rp = lane >> 5;       // which of 2 interleaved row streams
    int zt = lane & 31;       // z position within ROI z-run
    bool zok = (zt < lz);

    const float* base = feat + (size_t)c * (D2 * DIM)
                      + (sx + bx0) * D2 + (sy + by0) * DIM + sz + zt;

    // Row walk rr = rp, rp+2, ... ; (x,y) tracked without division.
    // ny >= 2 guarantees: start y=rp < ny, and each +=2 wraps at most once.
    int x = 0, y = rp, rr = rp;
    float m = -FLT_MAX;
    int rounds = (nrows + 1) >> 1;
    int batches = (rounds + 3) >> 2;      // <= 7, avg 2
    for (int b = 0; b < batches; ++b) {
        float v0 = -FLT_MAX, v1 = -FLT_MAX, v2 = -FLT_MAX, v3 = -FLT_MAX;
        if (zok && rr < nrows) v0 = base[x * D2 + y * DIM];
        y += 2; if (y >= ny) { y -= ny; ++x; } rr += 2;
        if (zok && rr < nrows) v1 = base[x * D2 + y * DIM];
        y += 2; if (y >= ny) { y -= ny; ++x; } rr += 2;
        if (zok && rr < nrows) v2 = base[x * D2 + y * DIM];
        y += 2; if (y >= ny) { y -= ny; ++x; } rr += 2;
        if (zok && rr < nrows) v3 = base[x * D2 + y * DIM];
        y += 2; if (y >= ny) { y -= ny; ++x; } rr += 2;
        m = fmaxf(m, fmaxf(fmaxf(v0, v1), fmaxf(v2, v3)));
    }

    // combine the two row streams: lanes 0..31 now hold per-z max
    m = fmaxf(m, __shfl_xor(m, 32));

    // segmented z-bin max: lane k in 0..3 gathers its bin's z range
    int k = lane & 3;
    int zb0 = (k * lz) >> 2;
    int zb1 = ((k + 1) * lz + 3) >> 2;    // span <= 7
    float mk = -FLT_MAX;
    #pragma unroll
    for (int s = 0; s < 7; ++s) {
        int idx = zb0 + s;                 // <= 18+6 = 24 < 32, safe
        float v = __shfl(m, idx);
        if (idx < zb1) mk = fmaxf(mk, v);
    }

    if (lane < 4)
        out[(((n << 6) | c) << 6) | (i << 4) | (j << 2) | k] = mk;
}

extern "C" void kernel_launch(void* const* d_in, const int* in_sizes, int n_in,
                              void* d_out, int out_size, void* d_ws, size_t ws_size,
                              hipStream_t stream) {
    const float* feat = (const float*)d_in[0];
    const int*   rois = (const int*)d_in[1];
    float*       out  = (float*)d_out;

    roipool3d_kernel<<<dim3(NROI * NC * 4), dim3(256), 0, stream>>>(feat, rois, out);
}